// Round 4
// baseline (115.116 us; speedup 1.0000x reference)
//
#include <hip/hip_runtime.h>

// ContrastiveEmbeddingLoss, N=8192, D=128, C=100, margin=1.
// loss = [ sum_{y_i!=y_j} d_ij + N*margin + sum_{same,i!=j} max(margin-d_ij,0) ] / N^2
//   dissim = 2*sum_c SQ_c*(N - n_c) - 2*||S||^2 + 2*SSsum
//     SQ_c = sum_{i in c}||x_i||^2,  S = sum_i x_i,  SSsum = sum_c sum_{a,b in c} x_a.x_b
// Only same-class pairs (~N^2/100) need explicit d -> per-class fp16 MFMA Gram.
//
// v4: 3 nodes, NO dependent wide stores (v3's fused-placement regression was
// the 256B gh store waiting on a contended cross-XCD atomic; the old rank
// kernel existed precisely to avoid that). Fix: store rows BY ROW INDEX
// (ghrow[r], independent of atomics); the atomic feeds only a 4-byte
// idx[c][slot]=r store. Gram gathers rows through idx (clamped for pads).
//   memset(7.5KB) -> scan (coalesced pass + row store + idx + stats)
//                 -> gram (800 blocks; last block finalizes via done-counter)

#define N_ROWS 8192
#define DIM    128
#define NCLS   100
#define CAP    224            // Binom(8192,0.01): mean 82, sd 9 -> +15 sigma
#define SCB    1024           // scan blocks (8 rows each)
#define GBPC   8              // gram blocks per class
#define GRAMB  (NCLS * GBPC)  // 800
#define NREP   8              // atomic replication for Scol/SQc

typedef _Float16 half8  __attribute__((ext_vector_type(8)));
typedef _Float16 half4v __attribute__((ext_vector_type(4)));
typedef float    float4v __attribute__((ext_vector_type(4)));

// ---------------- Kernel 0: one coalesced pass over x ----------------------
// ghrow[r][128] fp16 (row-indexed!), sqn[r], idx[c][slot]=r,
// Scol8[NREP][128], SQc8[NREP][100]. Only the 4B idx store depends on the
// placement atomic; the 256B row store is address-independent of it.
__global__ __launch_bounds__(256) void scan_kernel(
    const float* __restrict__ x, const int* __restrict__ y,
    int* __restrict__ cnt, int* __restrict__ idx,
    _Float16* __restrict__ ghrow, float* __restrict__ sqn,
    float* __restrict__ Scol8, float* __restrict__ SQc8)
{
    const int b = blockIdx.x, tid = threadIdx.x;
    const int l = tid & 31, g = tid >> 5;            // 32 lanes/row, 8 rows/blk
    const int r = b * 8 + g;
    const int rep = b & (NREP - 1);
    const float4* x4 = (const float4*)x;
    __shared__ float4 colred[256];

    float4 v = x4[r * 32 + l];                       // fully coalesced
    half4v h;
    h[0] = (_Float16)v.x; h[1] = (_Float16)v.y;
    h[2] = (_Float16)v.z; h[3] = (_Float16)v.w;
    *(half4v*)(ghrow + (size_t)r * DIM + l * 4) = h; // independent, coalesced

    float s = v.x*v.x + v.y*v.y + v.z*v.z + v.w*v.w;
    s += __shfl_xor(s, 1);  s += __shfl_xor(s, 2);  s += __shfl_xor(s, 4);
    s += __shfl_xor(s, 8);  s += __shfl_xor(s, 16);  // row sqnorm
    const int c = y[r];                              // uniform per group
    if (l == 0) {
        sqn[r] = s;                                  // row-indexed, independent
        atomicAdd(&SQc8[rep * NCLS + c], s);         // ~10-way contention
        const int p = atomicAdd(&cnt[c], 1);         // slot: unique, unordered
        if (p < CAP) idx[c * CAP + p] = r;           // only 4B depends on it
    }

    colred[tid] = v;
    __syncthreads();
    if (tid < 32) {
        float4 a = colred[tid];
        #pragma unroll
        for (int gg = 1; gg < 8; ++gg) {
            float4 t = colred[tid + 32 * gg];
            a.x += t.x; a.y += t.y; a.z += t.z; a.w += t.w;
        }
        float* dst = Scol8 + rep * DIM;              // ~128-way contention
        atomicAdd(&dst[4 * tid + 0], a.x);
        atomicAdd(&dst[4 * tid + 1], a.y);
        atomicAdd(&dst[4 * tid + 2], a.z);
        atomicAdd(&dst[4 * tid + 3], a.w);
    }
}

// ------- Kernel 1: per-class MFMA Gram hinge (8 blocks/class) + finalize ----
__global__ __launch_bounds__(256) void gram_kernel(
    const _Float16* __restrict__ ghrow, const float* __restrict__ sqn,
    const int* __restrict__ idx, const int* __restrict__ cnt,
    const float* __restrict__ Scol8, const float* __restrict__ SQc8,
    float* __restrict__ Hsum, float* __restrict__ SSsum,
    int* __restrict__ done, float* __restrict__ out)
{
    const int c = blockIdx.x >> 3, qq = blockIdx.x & 7, tid = threadIdx.x;
    __shared__ float wred[8];
    __shared__ int   lastFlag;

    const int mtrue = cnt[c];
    const int m = mtrue < CAP ? mtrue : CAP;
    const int ntiles = (m + 15) >> 4;
    const int ntp = ntiles * (ntiles + 1) / 2;       // ~21 for m~82

    const int wave = tid >> 6, lane = tid & 63;
    const int lr = lane & 15, q = lane >> 4;
    float hacc = 0.f, dsum = 0.f;
    const int cbase = c * CAP;

    // 32 waves/class: almost always <=1 tile-pair per wave.
    for (int tp = qq * 4 + wave; tp < ntp; tp += 32) {
        int ta = 0, rem = tp;
        while (rem >= ntiles - ta) { rem -= ntiles - ta; ++ta; }
        const int tb = ta + rem;
        // Pad lanes clamp the INDEX (poison idx never dereferenced); all
        // gathered rows are real data (no NaN/Inf). Outputs gated below.
        const int raI = ta * 16 + lr, rbI = tb * 16 + lr;
        const int rowA = idx[cbase + (raI < m ? raI : m - 1)];
        const int rowB = idx[cbase + (rbI < m ? rbI : m - 1)];
        const half8* ap = (const half8*)(ghrow + (size_t)rowA * DIM + q * 8);
        const half8* bp = (const half8*)(ghrow + (size_t)rowB * DIM + q * 8);
        float4v acc = {0.f, 0.f, 0.f, 0.f};
        #pragma unroll
        for (int kb = 0; kb < 4; ++kb)               // +32 halves per K block
            acc = __builtin_amdgcn_mfma_f32_16x16x32_f16(ap[kb * 4], bp[kb * 4], acc, 0, 0, 0);
        const float w = (ta == tb) ? 1.f : 2.f;
        const int bb = rbI;                          // C/D col = lane & 15
        const float sqb = (bb < m) ? sqn[rowB] : 0.f;
        const float sqa_own = sqn[rowA];             // this lane's A-row norm
        #pragma unroll
        for (int i = 0; i < 4; ++i) {
            const int a = ta * 16 + q * 4 + i;       // C/D row = quad*4 + reg
            // A-row a's norm lives in the lane with lr == q*4+i:
            const float sqa = __shfl(sqa_own, q * 4 + i, 16);
            if (a < m && bb < m) {
                const float dot = acc[i];
                dsum += w * dot;                     // includes diagonal a==bb
                if (a != bb) {
                    float d = fmaxf(sqa + sqb - 2.f * dot, 0.f);
                    hacc += w * fmaxf(1.f - d, 0.f);
                }
            }
        }
    }
    #pragma unroll
    for (int off = 32; off > 0; off >>= 1) {
        hacc += __shfl_xor(hacc, off);
        dsum += __shfl_xor(dsum, off);
    }
    if (lane == 0) { wred[wave] = hacc; wred[4 + wave] = dsum; }
    __syncthreads();
    if (tid == 0) {
        float h = wred[0] + wred[1] + wred[2] + wred[3];
        float d = wred[4] + wred[5] + wred[6] + wred[7];
        if (h != 0.f) atomicAdd(Hsum, h);
        if (d != 0.f) atomicAdd(SSsum, d);
        __threadfence();                             // release before counting
        int p = atomicAdd(done, 1);
        lastFlag = (p == GRAMB - 1);
    }
    __syncthreads();
    if (!lastFlag) return;

    // ---------------- fused finalize (last-arriving block only) ------------
    __threadfence();                                 // acquire others' results
    const double Nf = (double)N_ROWS;
    double contrib = 0.0;
    if (tid < DIM) {                                 // -2 ||S||^2
        float sc = 0.f;
        #pragma unroll
        for (int k = 0; k < NREP; ++k) sc += Scol8[k * DIM + tid];
        contrib -= 2.0 * (double)sc * (double)sc;
    }
    if (tid < NCLS) {                                // 2 SQ_c (N - n_c)
        float qv = 0.f;
        #pragma unroll
        for (int k = 0; k < NREP; ++k) qv += SQc8[k * NCLS + tid];
        contrib += 2.0 * (double)qv * (Nf - (double)cnt[tid]);
    }
    if (tid == 0) {
        float H  = __hip_atomic_load(Hsum,  __ATOMIC_RELAXED, __HIP_MEMORY_SCOPE_AGENT);
        float SS = __hip_atomic_load(SSsum, __ATOMIC_RELAXED, __HIP_MEMORY_SCOPE_AGENT);
        contrib += 2.0 * (double)SS + (double)H + Nf * 1.0 /* N*margin */;
    }
    __shared__ double dred[256];
    dred[tid] = contrib;
    __syncthreads();
    for (int s = 128; s > 0; s >>= 1) {
        if (tid < s) dred[tid] += dred[tid + s];
        __syncthreads();
    }
    if (tid == 0) out[0] = (float)(dred[0] / (Nf * Nf));
}

extern "C" void kernel_launch(void* const* d_in, const int* in_sizes, int n_in,
                              void* d_out, int out_size, void* d_ws, size_t ws_size,
                              hipStream_t stream) {
    const float* x = (const float*)d_in[0];
    const int*   y = (const int*)d_in[1];

    _Float16* ghrow = (_Float16*)d_ws;                        // 8192*128 fp16 = 2 MB
    float* sqn   = (float*)(ghrow + (size_t)N_ROWS * DIM);    // 8192
    int*   idx   = (int*)(sqn + N_ROWS);                      // 100*224
    // ---- zero region (single small memset): ----
    float* Scol8 = (float*)(idx + NCLS * CAP); // NREP*128
    float* SQc8  = Scol8 + NREP * DIM;         // NREP*100
    float* Hsum  = SQc8 + NREP * NCLS;         // 1
    float* SSsum = Hsum + 1;                   // 1
    int*   cnt   = (int*)(SSsum + 1);          // 100
    int*   done  = cnt + NCLS;                 // 1
    const size_t zero_words = NREP * DIM + NREP * NCLS + 2 + NCLS + 1; // 1927

    hipMemsetAsync(Scol8, 0, zero_words * sizeof(float), stream);
    scan_kernel<<<SCB,   256, 0, stream>>>(x, y, cnt, idx, ghrow, sqn,
                                           Scol8, SQc8);
    gram_kernel<<<GRAMB, 256, 0, stream>>>(ghrow, sqn, idx, cnt, Scol8, SQc8,
                                           Hsum, SSsum, done, (float*)d_out);
}

// Round 5
// 106.293 us; speedup vs baseline: 1.0830x; 1.0830x over previous
//
#include <hip/hip_runtime.h>

// ContrastiveEmbeddingLoss, N=8192, D=128, C=100, margin=1.
// loss = [ sum_{y_i!=y_j} d_ij + N*margin + sum_{same,i!=j} max(margin-d_ij,0) ] / N^2
//   dissim = 2*sum_c SQ_c*(N - n_c) - 2*||S||^2 + 2*SSsum
//     SQ_c = sum_{i in c}||x_i||^2,  S = sum_i x_i,  SSsum = sum_c sum_{a,b in c} x_a.x_b
// Only same-class pairs (~N^2/100) need explicit d -> per-class fp16 MFMA Gram.
//
// v5: placement atomics eliminated ENTIRELY (v3/v4 showed +18us from 8192
// contended cross-XCD atomicAdd(&cnt[c]) with used return in scan; v4 proved
// it was the atomic itself, not the dependent store). Each gram block builds
// its class's row list locally from y via deterministic ballot/prefix-popcount
// (identical list across the 8 blocks of a class). Scan is a pure stream.
//   memset(4.1KB) -> scan (x -> ghrow fp16 + sqn + Scol8)
//                 -> gram (800 blocks; qq==0 also computes 2*SQ_c*(N-n_c);
//                    last block finalizes via done-counter)

#define N_ROWS 8192
#define DIM    128
#define NCLS   100
#define CAP    224            // Binom(8192,0.01): mean 82, sd 9 -> +15 sigma
#define SCB    1024           // scan blocks (8 rows each)
#define GBPC   8              // gram blocks per class
#define GRAMB  (NCLS * GBPC)  // 800
#define NREP   8              // atomic replication for Scol

typedef _Float16 half8  __attribute__((ext_vector_type(8)));
typedef _Float16 half4v __attribute__((ext_vector_type(4)));
typedef float    float4v __attribute__((ext_vector_type(4)));

// ---------------- Kernel 0: pure streaming pass over x ---------------------
// ghrow[r][128] fp16 (row-indexed), sqn[r], Scol8[NREP][128] column sums.
// No y read, no placement, no per-row global atomics.
__global__ __launch_bounds__(256) void scan_kernel(
    const float* __restrict__ x,
    _Float16* __restrict__ ghrow, float* __restrict__ sqn,
    float* __restrict__ Scol8)
{
    const int b = blockIdx.x, tid = threadIdx.x;
    const int l = tid & 31, g = tid >> 5;            // 32 lanes/row, 8 rows/blk
    const int r = b * 8 + g;
    const int rep = b & (NREP - 1);
    const float4* x4 = (const float4*)x;
    __shared__ float4 colred[256];

    float4 v = x4[r * 32 + l];                       // fully coalesced
    half4v h;
    h[0] = (_Float16)v.x; h[1] = (_Float16)v.y;
    h[2] = (_Float16)v.z; h[3] = (_Float16)v.w;
    *(half4v*)(ghrow + (size_t)r * DIM + l * 4) = h; // independent, coalesced

    float s = v.x*v.x + v.y*v.y + v.z*v.z + v.w*v.w;
    s += __shfl_xor(s, 1);  s += __shfl_xor(s, 2);  s += __shfl_xor(s, 4);
    s += __shfl_xor(s, 8);  s += __shfl_xor(s, 16);  // row sqnorm
    if (l == 0) sqn[r] = s;                          // row-indexed store

    colred[tid] = v;
    __syncthreads();
    if (tid < 32) {
        float4 a = colred[tid];
        #pragma unroll
        for (int gg = 1; gg < 8; ++gg) {
            float4 t = colred[tid + 32 * gg];
            a.x += t.x; a.y += t.y; a.z += t.z; a.w += t.w;
        }
        float* dst = Scol8 + rep * DIM;              // ~128-way contention
        atomicAdd(&dst[4 * tid + 0], a.x);
        atomicAdd(&dst[4 * tid + 1], a.y);
        atomicAdd(&dst[4 * tid + 2], a.z);
        atomicAdd(&dst[4 * tid + 3], a.w);
    }
}

// ------- Kernel 1: per-class MFMA Gram hinge (8 blocks/class) + finalize ----
// Each block rebuilds its class's row list from y (deterministic: ballot +
// prefix popcount in fixed row order -> identical across the class's blocks).
__global__ __launch_bounds__(256) void gram_kernel(
    const _Float16* __restrict__ ghrow, const float* __restrict__ sqn,
    const int* __restrict__ y,
    const float* __restrict__ Scol8,
    float* __restrict__ Hsum, float* __restrict__ SSsum,
    double* __restrict__ Dterm,
    int* __restrict__ done, float* __restrict__ out)
{
    const int c = blockIdx.x >> 3, qq = blockIdx.x & 7, tid = threadIdx.x;
    __shared__ int   lidx[CAP];
    __shared__ int   lmv[2];                         // [0]=min(cnt,CAP) [1]=cnt
    __shared__ float wred[12];
    __shared__ int   lastFlag;

    // ---- deterministic list build (wave 0 only; ~32 KB of y, L2-resident) --
    if (tid < 64) {
        int base = 0;
        const int4* y4 = (const int4*)y;
        int4 vv = y4[tid];                           // prefetched
        for (int it = 0; it < N_ROWS / 256; ++it) {  // 32 iterations
            const int4 cur = vv;
            if (it < N_ROWS / 256 - 1) vv = y4[(it + 1) * 64 + tid];
            const int rbase = (it * 64 + tid) * 4;
            #pragma unroll
            for (int j = 0; j < 4; ++j) {
                const int yi = (j == 0) ? cur.x : (j == 1) ? cur.y
                             : (j == 2) ? cur.z : cur.w;
                const unsigned long long mb = __ballot(yi == c);
                if (yi == c) {
                    const int pos = base +
                        (int)__popcll(mb & ((1ull << tid) - 1ull));
                    if (pos < CAP) lidx[pos] = rbase + j;
                }
                base += (int)__popcll(mb);
            }
        }
        if (tid == 0) { lmv[1] = base; lmv[0] = base < CAP ? base : CAP; }
    }
    __syncthreads();
    const int m = lmv[0], mt = lmv[1];

    const int ntiles = (m + 15) >> 4;
    const int ntp = ntiles * (ntiles + 1) / 2;       // ~21 for m~82

    const int wave = tid >> 6, lane = tid & 63;
    const int lr = lane & 15, q = lane >> 4;
    float hacc = 0.f, dsum = 0.f;

    // qq==0 block also gathers SQ_c = sum sqn over the class list (m<=224<256)
    float qv = (qq == 0 && tid < m) ? sqn[lidx[tid]] : 0.f;

    // 32 waves/class: almost always <=1 tile-pair per wave.
    for (int tp = qq * 4 + wave; tp < ntp; tp += 32) {
        int ta = 0, rem = tp;
        while (rem >= ntiles - ta) { rem -= ntiles - ta; ++ta; }
        const int tb = ta + rem;
        // Pad lanes clamp the LIST INDEX; all gathered rows are real data
        // (no NaN/Inf). Outputs gated below.
        const int raI = ta * 16 + lr, rbI = tb * 16 + lr;
        const int rowA = lidx[raI < m ? raI : m - 1];
        const int rowB = lidx[rbI < m ? rbI : m - 1];
        const half8* ap = (const half8*)(ghrow + (size_t)rowA * DIM + q * 8);
        const half8* bp = (const half8*)(ghrow + (size_t)rowB * DIM + q * 8);
        float4v acc = {0.f, 0.f, 0.f, 0.f};
        #pragma unroll
        for (int kb = 0; kb < 4; ++kb)               // +32 halves per K block
            acc = __builtin_amdgcn_mfma_f32_16x16x32_f16(ap[kb * 4], bp[kb * 4], acc, 0, 0, 0);
        const float w = (ta == tb) ? 1.f : 2.f;
        const int bb = rbI;                          // C/D col = lane & 15
        const float sqb = (bb < m) ? sqn[rowB] : 0.f;
        const float sqa_own = sqn[rowA];             // this lane's A-row norm
        #pragma unroll
        for (int i = 0; i < 4; ++i) {
            const int a = ta * 16 + q * 4 + i;       // C/D row = quad*4 + reg
            // A-row a's norm lives in the lane with lr == q*4+i:
            const float sqa = __shfl(sqa_own, q * 4 + i, 16);
            if (a < m && bb < m) {
                const float dot = acc[i];
                dsum += w * dot;                     // includes diagonal a==bb
                if (a != bb) {
                    float d = fmaxf(sqa + sqb - 2.f * dot, 0.f);
                    hacc += w * fmaxf(1.f - d, 0.f);
                }
            }
        }
    }
    #pragma unroll
    for (int off = 32; off > 0; off >>= 1) {
        hacc += __shfl_xor(hacc, off);
        dsum += __shfl_xor(dsum, off);
        qv   += __shfl_xor(qv,   off);
    }
    if (lane == 0) { wred[wave] = hacc; wred[4 + wave] = dsum; wred[8 + wave] = qv; }
    __syncthreads();
    if (tid == 0) {
        float h = wred[0] + wred[1] + wred[2] + wred[3];
        float d = wred[4] + wred[5] + wred[6] + wred[7];
        if (qq == 0) {                               // class dissim term
            float qs = wred[8] + wred[9] + wred[10] + wred[11];
            Dterm[c] = 2.0 * (double)qs * ((double)N_ROWS - (double)mt);
        }
        if (h != 0.f) atomicAdd(Hsum, h);
        if (d != 0.f) atomicAdd(SSsum, d);
        __threadfence();                             // release before counting
        int p = atomicAdd(done, 1);
        lastFlag = (p == GRAMB - 1);
    }
    __syncthreads();
    if (!lastFlag) return;

    // ---------------- fused finalize (last-arriving block only) ------------
    __threadfence();                                 // acquire others' results
    const double Nf = (double)N_ROWS;
    double contrib = 0.0;
    if (tid < DIM) {                                 // -2 ||S||^2
        float sc = 0.f;
        #pragma unroll
        for (int k = 0; k < NREP; ++k) sc += Scol8[k * DIM + tid];
        contrib -= 2.0 * (double)sc * (double)sc;
    }
    if (tid < NCLS) contrib += Dterm[tid];           // 2 SQ_c (N - n_c)
    if (tid == 0) {
        float H  = __hip_atomic_load(Hsum,  __ATOMIC_RELAXED, __HIP_MEMORY_SCOPE_AGENT);
        float SS = __hip_atomic_load(SSsum, __ATOMIC_RELAXED, __HIP_MEMORY_SCOPE_AGENT);
        contrib += 2.0 * (double)SS + (double)H + Nf * 1.0 /* N*margin */;
    }
    __shared__ double dred[256];
    dred[tid] = contrib;
    __syncthreads();
    for (int s = 128; s > 0; s >>= 1) {
        if (tid < s) dred[tid] += dred[tid + s];
        __syncthreads();
    }
    if (tid == 0) out[0] = (float)(dred[0] / (Nf * Nf));
}

extern "C" void kernel_launch(void* const* d_in, const int* in_sizes, int n_in,
                              void* d_out, int out_size, void* d_ws, size_t ws_size,
                              hipStream_t stream) {
    const float* x = (const float*)d_in[0];
    const int*   y = (const int*)d_in[1];

    _Float16* ghrow = (_Float16*)d_ws;                        // 8192*128 fp16 = 2 MB
    float* sqn   = (float*)(ghrow + (size_t)N_ROWS * DIM);    // 8192
    // ---- zero region (single small memset): ----
    float* Scol8 = sqn + N_ROWS;               // NREP*128
    float* Hsum  = Scol8 + NREP * DIM;         // 1
    float* SSsum = Hsum + 1;                   // 1
    int*   done  = (int*)(SSsum + 1);          // 1
    const size_t zero_words = NREP * DIM + 3;  // 1027
    // ---- always-written region (no memset needed): ----
    double* Dterm = (double*)(done + 1);       // 100 doubles (8B-aligned: 1024+3+1 ints from 8B base -> pad)

    hipMemsetAsync(Scol8, 0, zero_words * sizeof(float), stream);
    scan_kernel<<<SCB,   256, 0, stream>>>(x, ghrow, sqn, Scol8);
    gram_kernel<<<GRAMB, 256, 0, stream>>>(ghrow, sqn, y, Scol8,
                                           Hsum, SSsum, Dterm, done,
                                           (float*)d_out);
}